// Round 5
// baseline (131.304 us; speedup 1.0000x reference)
//
#include <hip/hip_runtime.h>

typedef _Float16 half8 __attribute__((ext_vector_type(8)));
typedef _Float16 half4 __attribute__((ext_vector_type(4)));
typedef float floatx4 __attribute__((ext_vector_type(4)));

#define IN_DIM 256
#define OUT_DIM 256
#define M_TILE 32
#define ROWSTR 264  // 256 + 8 f16 pad: ds_read_b128 conflict-free (measured R2: SQ_LDS_BANK_CONFLICT=0)

// Quantize weight -> f16 in MFMA-A-fragment-permuted order:
//   perm[((ct*8 + ks)*64 + lane)*8 + e] = rne(W[ct*16 + (lane&15)][ks*32 + (lane>>4)*8 + e] * 100)
// Each gemm A-frag load is then one fully-coalesced 16B/lane dwordx4 from an
// L1/L2-hot 128KB buffer. Also quantizes bias and writes the scalar output.
__global__ void quant_kernel(const float* __restrict__ w,
                             const float* __restrict__ bias,
                             const float* __restrict__ in_scale,
                             _Float16* __restrict__ wqp,
                             float* __restrict__ bq,
                             float* __restrict__ out_scalar) {
    int t = blockIdx.x * blockDim.x + threadIdx.x;
    if (t < (OUT_DIM * IN_DIM) / 8) {
        int lane = t & 63;
        int ks   = (t >> 6) & 7;
        int ct   = t >> 9;
        int row  = ct * 16 + (lane & 15);
        int k0   = ks * 32 + (lane >> 4) * 8;
        const float* src = w + row * IN_DIM + k0;
        half8 h;
#pragma unroll
        for (int e = 0; e < 8; ++e)
            h[e] = (_Float16)rintf(src[e] * 100.0f); // jnp.round = round-half-even
        *((half8*)wqp + t) = h;
    }
    if (t < OUT_DIM) {
        float s2 = in_scale[0] * 100.0f;
        bq[t] = rintf(bias[t] * s2);
    }
    if (t == 0 && out_scalar != nullptr)
        out_scalar[0] = in_scale[0] * 100.0f;
}

// 32-row x 256-col tile per block, grid 2048 = 8 blocks/CU of work at 4
// resident -> two generations; gen-2 staging (HBM reads) overlaps gen-1
// compute/stores via HW dispatch. Wave w owns cols [w*64, w*64+64).
__global__ __launch_bounds__(256, 4) void gemm_kernel(const int* __restrict__ cx,
                                                      const _Float16* __restrict__ wqp,
                                                      const float* __restrict__ bq,
                                                      float* __restrict__ out) {
    __shared__ _Float16 buf[M_TILE * ROWSTR];

    const int t = threadIdx.x;
    const size_t m0 = (size_t)blockIdx.x * M_TILE;

    // ---- stage: explicit two-phase for full MLP (8 int4 loads in flight) ----
    const int* cbase = cx + m0 * IN_DIM;
    int4 v[8];
#pragma unroll
    for (int i = 0; i < 8; ++i)
        v[i] = *(const int4*)(cbase + i * 1024 + t * 4);
#pragma unroll
    for (int i = 0; i < 8; ++i) {
        int flat = i * 1024 + t * 4;
        int row = flat >> 8;
        int col = flat & 255;
        half4 h;
        h.x = (_Float16)v[i].x; h.y = (_Float16)v[i].y;
        h.z = (_Float16)v[i].z; h.w = (_Float16)v[i].w;
        *(half4*)&buf[row * ROWSTR + col] = h;
    }
    __syncthreads();

    const int wave = t >> 6;
    const int lane = t & 63;
    const int m16  = lane & 15;
    const int quad = lane >> 4;

    floatx4 acc[4][2] = {};   // [i: col tile][j: 16-row group] = 32 VGPRs

    const half8* wbase = (const half8*)wqp;
#pragma unroll
    for (int ks = 0; ks < 8; ++ks) {
        half8 afr[4], bfr[2];
#pragma unroll
        for (int i = 0; i < 4; ++i)   // W, coalesced, L1/L2-hot
            afr[i] = wbase[((wave * 4 + i) * 8 + ks) * 64 + lane];
        const int kb = ks * 32 + quad * 8;
#pragma unroll
        for (int j = 0; j < 2; ++j)   // c_x f16 from LDS, conflict-free
            bfr[j] = *(const half8*)&buf[(j * 16 + m16) * ROWSTR + kb];
#pragma unroll
        for (int i = 0; i < 4; ++i)
#pragma unroll
            for (int j = 0; j < 2; ++j)
                acc[i][j] = __builtin_amdgcn_mfma_f32_16x16x32_f16(afr[i], bfr[j], acc[i][j], 0, 0, 0);
    }

    // ---- epilogue: lane stores 4 consecutive out cols per tile as float4 ----
#pragma unroll
    for (int i = 0; i < 4; ++i) {
        int col = wave * 64 + i * 16 + quad * 4;
        floatx4 bv = *(const floatx4*)(bq + col);
#pragma unroll
        for (int j = 0; j < 2; ++j) {
            size_t row = m0 + j * 16 + m16;
            *(floatx4*)(out + row * OUT_DIM + col) = acc[i][j] + bv;
        }
    }
}

extern "C" void kernel_launch(void* const* d_in, const int* in_sizes, int n_in,
                              void* d_out, int out_size, void* d_ws, size_t ws_size,
                              hipStream_t stream) {
    const int*   cx       = (const int*)d_in[0];
    const float* w        = (const float*)d_in[1];
    const float* bias     = (const float*)d_in[2];
    const float* in_scale = (const float*)d_in[3];
    float* out = (float*)d_out;

    _Float16* wqp = (_Float16*)d_ws;                              // 128 KB, permuted
    float*    bq  = (float*)((char*)d_ws + OUT_DIM * IN_DIM * 2); // 1 KB

    const int rows = in_sizes[0] / IN_DIM;          // 65536
    const size_t gemm_elems = (size_t)rows * OUT_DIM;
    float* out_scalar = ((size_t)out_size > gemm_elems) ? (out + gemm_elems) : nullptr;

    quant_kernel<<<32, 256, 0, stream>>>(w, bias, in_scale, wqp, bq, out_scalar);
    gemm_kernel<<<rows / M_TILE, 256, 0, stream>>>(cx, wqp, bq, out);
}